// Round 1
// baseline (170.807 us; speedup 1.0000x reference)
//
#include <hip/hip_runtime.h>
#include <hip/hip_bf16.h>

#define BATCH 8192
#define IN_F  2048
#define OUT_F 2048
#define QB    7.0f
#define EPSV  1e-5f
#define ASCALE 18.0f            // xq_i8 = round(xq * 18) in [-126,126]

typedef char  i8x4 __attribute__((ext_vector_type(4)));
typedef int   i32x4 __attribute__((ext_vector_type(4)));

#define AS1(p) ((__attribute__((address_space(1))) void*)(p))
#define AS3(p) ((__attribute__((address_space(3))) void*)(p))

// ---------------- Fused preprocessing, one WAVE per row ----------------
// No LDS, no __syncthreads: each 64-lane wave owns one row.
// waves [0, OUT_F): weight row -> wbin i8 {-1,0,1} (exact), beta
// waves [OUT_F, OUT_F+BATCH): LN+clip row -> xq i8 = round(clip*18), gama
// Lane j holds float4 elements {lane + 64*j}, j=0..7 -> 128 B/lane in flight
// before the first dependent use (4x the old block-per-row version).
__global__ __launch_bounds__(256) void prep_kernel(const float* __restrict__ x,
                                                   const float* __restrict__ w,
                                                   char* __restrict__ xq,
                                                   char* __restrict__ wb,
                                                   float* __restrict__ gamaOut,
                                                   float* __restrict__ betaOut) {
  const int t = threadIdx.x;
  const int wave = t >> 6, lane = t & 63;
  const int rowId = blockIdx.x * 4 + wave;   // grid = (OUT_F + BATCH) / 4

  if (rowId < OUT_F) {
    // ---- weight row: mean-center sign + mean(|w|) ----
    const int row = rowId;
    const float4* wr = (const float4*)(w + (size_t)row * IN_F);
    float4 v[8];
#pragma unroll
    for (int j = 0; j < 8; ++j) v[j] = wr[lane + 64 * j];

    float s = 0.0f, sa = 0.0f;
#pragma unroll
    for (int j = 0; j < 8; ++j) {
      s  += v[j].x + v[j].y + v[j].z + v[j].w;
      sa += fabsf(v[j].x) + fabsf(v[j].y) + fabsf(v[j].z) + fabsf(v[j].w);
    }
#pragma unroll
    for (int off = 32; off > 0; off >>= 1) {
      s  += __shfl_xor(s, off, 64);
      sa += __shfl_xor(sa, off, 64);
    }
    const float mu = s * (1.0f / IN_F);
    if (lane == 0) betaOut[row] = sa * (1.0f / IN_F);

    char* wbr = wb + (size_t)row * IN_F;
    auto sgn = [&](float xv) -> char {
      float d = xv - mu;
      return (char)((d > 0.0f) ? 1 : (d < 0.0f ? -1 : 0));
    };
#pragma unroll
    for (int j = 0; j < 8; ++j) {
      i8x4 q = { sgn(v[j].x), sgn(v[j].y), sgn(v[j].z), sgn(v[j].w) };
      ((i8x4*)wbr)[lane + 64 * j] = q;
    }
  } else {
    // ---- x row: LN (no affine) + abs-max + 4-bit-range quant to i8*18 ----
    const int row = rowId - OUT_F;
    const float4* xr = (const float4*)(x + (size_t)row * IN_F);
    float4 v[8];
#pragma unroll
    for (int j = 0; j < 8; ++j) v[j] = xr[lane + 64 * j];

    float s = 0.0f, s2 = 0.0f;
#pragma unroll
    for (int j = 0; j < 8; ++j) {
      s  += v[j].x + v[j].y + v[j].z + v[j].w;
      s2 += v[j].x * v[j].x + v[j].y * v[j].y + v[j].z * v[j].z + v[j].w * v[j].w;
    }
#pragma unroll
    for (int off = 32; off > 0; off >>= 1) {
      s  += __shfl_xor(s, off, 64);
      s2 += __shfl_xor(s2, off, 64);
    }
    const float mu   = s * (1.0f / IN_F);
    const float rstd = rsqrtf(fmaxf(s2 * (1.0f / IN_F) - mu * mu, 0.0f) + EPSV);

    // gama = max(rstd * max|v - mu|, eps)  (== max over normalized values)
    float ad = 0.0f;
#pragma unroll
    for (int j = 0; j < 8; ++j) {
      ad = fmaxf(ad, fmaxf(fmaxf(fabsf(v[j].x - mu), fabsf(v[j].y - mu)),
                           fmaxf(fabsf(v[j].z - mu), fabsf(v[j].w - mu))));
    }
#pragma unroll
    for (int off = 32; off > 0; off >>= 1) ad = fmaxf(ad, __shfl_xor(ad, off, 64));
    const float g = fmaxf(ad * rstd, EPSV);
    if (lane == 0) gamaOut[row] = g;

    // xq_i8 = round( clip((v-mu)*rstd * 7/g, -(7-eps), 7-eps) * 18 )
    const float c  = rstd * (QB * ASCALE) / g;     // rstd * 126/g
    const float lo = (-QB + EPSV) * ASCALE, hi = (QB - EPSV) * ASCALE;
    auto qz = [&](float vv) -> char {
      return (char)__float2int_rn(fminf(fmaxf((vv - mu) * c, lo), hi));
    };
    char* xqr = xq + (size_t)row * IN_F;
#pragma unroll
    for (int j = 0; j < 8; ++j) {
      i8x4 q = { qz(v[j].x), qz(v[j].y), qz(v[j].z), qz(v[j].w) };
      ((i8x4*)xqr)[lane + 64 * j] = q;
    }
  }
}

// ---------------- GEMM: i8, 128x128 tile, BK=128 elems (128 B rows) ----------
// out[b,o] = i32dot(xq_i8[b,:], wbin[o,:]) * beta[o]*gama[b]/(7*18) + bias[o]
// Exact r2-proven LDS scheme: rows of 128 B = 8 chunks of 16 B; slot s of row
// r holds global chunk (s-r)&7; fragment read of chunk kh from row fr hits
// slot (kh+fr)&7 -> per 16-lane group each bank-quad 2x (measured 0 conflicts).
// 4 waves 2x2, wave = 64x64 via 4x4 of 16x16x64 i8 MFMA; 16 K-iters.
__global__ __launch_bounds__(256) void gemm_kernel(const char* __restrict__ A,
                                                   const char* __restrict__ B,
                                                   const float* __restrict__ beta,
                                                   const float* __restrict__ gama,
                                                   const float* __restrict__ bias,
                                                   float* __restrict__ out) {
  __shared__ __align__(16) char As[128 * 128];
  __shared__ __align__(16) char Bs[128 * 128];

  const int t = threadIdx.x;
  const int wave = t >> 6, lane = t & 63;
  const int mBase = blockIdx.y * 128;
  const int nBase = blockIdx.x * 128;
  const int wm = (wave >> 1) * 64;
  const int wn = (wave & 1) * 64;

  i32x4 acc[4][4];
#pragma unroll
  for (int i = 0; i < 4; ++i)
#pragma unroll
    for (int j = 0; j < 4; ++j) {
      i32x4 z = {0, 0, 0, 0};
      acc[i][j] = z;
    }

  // ---- staging: instr j covers rows j*32 + wave*8 + (lane>>3); slot = lane&7
  // fetch global chunk (slot - row)&7  (row base == 0 mod 8 -> (ls - lr)&7)
  const int lr = lane >> 3;
  const int ls = lane & 7;
  const int gch = (ls - lr) & 7;
  const char* aG[4];
  const char* bG[4];
  char* aL[4];
  char* bL[4];
#pragma unroll
  for (int j = 0; j < 4; ++j) {
    const int rowInTile = j * 32 + wave * 8 + lr;
    aG[j] = A + (size_t)(mBase + rowInTile) * IN_F + gch * 16;
    bG[j] = B + (size_t)(nBase + rowInTile) * IN_F + gch * 16;
    aL[j] = As + (j * 32 + wave * 8) * 128;   // wave-uniform; HW adds lane*16B
    bL[j] = Bs + (j * 32 + wave * 8) * 128;
  }

  // ---- fragment: A[m=lane&15][k = (lane>>4)*16 + j], j=0..15 (16B chunk)
  // k-chunk kh = ks*4 + kq ; slot = (kh + fr) & 7
  const int fr = lane & 15;
  const int kq = lane >> 4;            // 0..3
  const char* aF = As + (wm + fr) * 128;
  const char* bF = Bs + (wn + fr) * 128;
  int koff[2];
#pragma unroll
  for (int ks = 0; ks < 2; ++ks) koff[ks] = ((ks * 4 + kq + fr) & 7) * 16;

  for (int k0 = 0; k0 < IN_F; k0 += 128) {
#pragma unroll
    for (int j = 0; j < 4; ++j) {
      __builtin_amdgcn_global_load_lds(AS1(aG[j] + k0), AS3(aL[j]), 16, 0, 0);
      __builtin_amdgcn_global_load_lds(AS1(bG[j] + k0), AS3(bL[j]), 16, 0, 0);
    }
    __syncthreads();

#pragma unroll
    for (int ks = 0; ks < 2; ++ks) {
      i32x4 af[4], bf[4];
#pragma unroll
      for (int mi = 0; mi < 4; ++mi) af[mi] = *(const i32x4*)(aF + mi * 16 * 128 + koff[ks]);
#pragma unroll
      for (int ni = 0; ni < 4; ++ni) bf[ni] = *(const i32x4*)(bF + ni * 16 * 128 + koff[ks]);
#pragma unroll
      for (int mi = 0; mi < 4; ++mi)
#pragma unroll
        for (int ni = 0; ni < 4; ++ni)
          acc[mi][ni] = __builtin_amdgcn_mfma_i32_16x16x64_i8(af[mi], bf[ni], acc[mi][ni], 0, 0, 0);
    }
    __syncthreads();
  }

  // ---- epilogue: C/D layout col = lane&15, row = (lane>>4)*4 + reg
  const float qinv = 1.0f / (QB * ASCALE);
  const int orow0 = mBase + wm + (kq << 2);
  const int ocol0 = nBase + wn + fr;
#pragma unroll
  for (int mi = 0; mi < 4; ++mi) {
    const int rbase = orow0 + mi * 16;
    const float g0 = gama[rbase + 0] * qinv;
    const float g1 = gama[rbase + 1] * qinv;
    const float g2 = gama[rbase + 2] * qinv;
    const float g3 = gama[rbase + 3] * qinv;
#pragma unroll
    for (int ni = 0; ni < 4; ++ni) {
      const int c = ocol0 + ni * 16;
      const float bsc = beta[c];
      const float bv  = bias[c];
      float* op = out + (size_t)rbase * OUT_F + c;
      op[0 * OUT_F] = (float)acc[mi][ni][0] * (bsc * g0) + bv;
      op[1 * OUT_F] = (float)acc[mi][ni][1] * (bsc * g1) + bv;
      op[2 * OUT_F] = (float)acc[mi][ni][2] * (bsc * g2) + bv;
      op[3 * OUT_F] = (float)acc[mi][ni][3] * (bsc * g3) + bv;
    }
  }
}

extern "C" void kernel_launch(void* const* d_in, const int* in_sizes, int n_in,
                              void* d_out, int out_size, void* d_ws, size_t ws_size,
                              hipStream_t stream) {
  const float* x      = (const float*)d_in[0];
  const float* weight = (const float*)d_in[1];
  const float* bias   = (const float*)d_in[2];
  float* out = (float*)d_out;

  char* ws = (char*)d_ws;
  char* wbin = ws;                                                  // 4 MB
  char* xq   = ws + (size_t)OUT_F * IN_F;                           // 16 MB
  float* betaW = (float*)(ws + (size_t)OUT_F * IN_F + (size_t)BATCH * IN_F);
  float* gamaX = betaW + OUT_F;

  prep_kernel<<<(OUT_F + BATCH) / 4, 256, 0, stream>>>(x, weight, xq, wbin, gamaX, betaW);
  gemm_kernel<<<dim3(OUT_F / 128, BATCH / 128), 256, 0, stream>>>(xq, wbin, betaW, gamaX, bias, out);
}

// Round 3
// 166.812 us; speedup vs baseline: 1.0239x; 1.0239x over previous
//
#include <hip/hip_runtime.h>
#include <hip/hip_bf16.h>

#define BATCH 8192
#define IN_F  2048
#define OUT_F 2048
#define QB    7.0f
#define EPSV  1e-5f
#define ASCALE 18.0f            // xq_i8 = round(xq * 18) in [-126,126]

typedef char  i8x4 __attribute__((ext_vector_type(4)));
typedef int   i32x4 __attribute__((ext_vector_type(4)));

#define AS1(p) ((__attribute__((address_space(1))) void*)(p))
#define AS3(p) ((__attribute__((address_space(3))) void*)(p))

// ---------------- Fused preprocessing, one WAVE per row ----------------
// (round-1 verified version, unchanged)
__global__ __launch_bounds__(256) void prep_kernel(const float* __restrict__ x,
                                                   const float* __restrict__ w,
                                                   char* __restrict__ xq,
                                                   char* __restrict__ wb,
                                                   float* __restrict__ gamaOut,
                                                   float* __restrict__ betaOut) {
  const int t = threadIdx.x;
  const int wave = t >> 6, lane = t & 63;
  const int rowId = blockIdx.x * 4 + wave;   // grid = (OUT_F + BATCH) / 4

  if (rowId < OUT_F) {
    const int row = rowId;
    const float4* wr = (const float4*)(w + (size_t)row * IN_F);
    float4 v[8];
#pragma unroll
    for (int j = 0; j < 8; ++j) v[j] = wr[lane + 64 * j];

    float s = 0.0f, sa = 0.0f;
#pragma unroll
    for (int j = 0; j < 8; ++j) {
      s  += v[j].x + v[j].y + v[j].z + v[j].w;
      sa += fabsf(v[j].x) + fabsf(v[j].y) + fabsf(v[j].z) + fabsf(v[j].w);
    }
#pragma unroll
    for (int off = 32; off > 0; off >>= 1) {
      s  += __shfl_xor(s, off, 64);
      sa += __shfl_xor(sa, off, 64);
    }
    const float mu = s * (1.0f / IN_F);
    if (lane == 0) betaOut[row] = sa * (1.0f / IN_F);

    char* wbr = wb + (size_t)row * IN_F;
    auto sgn = [&](float xv) -> char {
      float d = xv - mu;
      return (char)((d > 0.0f) ? 1 : (d < 0.0f ? -1 : 0));
    };
#pragma unroll
    for (int j = 0; j < 8; ++j) {
      i8x4 q = { sgn(v[j].x), sgn(v[j].y), sgn(v[j].z), sgn(v[j].w) };
      ((i8x4*)wbr)[lane + 64 * j] = q;
    }
  } else {
    const int row = rowId - OUT_F;
    const float4* xr = (const float4*)(x + (size_t)row * IN_F);
    float4 v[8];
#pragma unroll
    for (int j = 0; j < 8; ++j) v[j] = xr[lane + 64 * j];

    float s = 0.0f, s2 = 0.0f;
#pragma unroll
    for (int j = 0; j < 8; ++j) {
      s  += v[j].x + v[j].y + v[j].z + v[j].w;
      s2 += v[j].x * v[j].x + v[j].y * v[j].y + v[j].z * v[j].z + v[j].w * v[j].w;
    }
#pragma unroll
    for (int off = 32; off > 0; off >>= 1) {
      s  += __shfl_xor(s, off, 64);
      s2 += __shfl_xor(s2, off, 64);
    }
    const float mu   = s * (1.0f / IN_F);
    const float rstd = rsqrtf(fmaxf(s2 * (1.0f / IN_F) - mu * mu, 0.0f) + EPSV);

    float ad = 0.0f;
#pragma unroll
    for (int j = 0; j < 8; ++j) {
      ad = fmaxf(ad, fmaxf(fmaxf(fabsf(v[j].x - mu), fabsf(v[j].y - mu)),
                           fmaxf(fabsf(v[j].z - mu), fabsf(v[j].w - mu))));
    }
#pragma unroll
    for (int off = 32; off > 0; off >>= 1) ad = fmaxf(ad, __shfl_xor(ad, off, 64));
    const float g = fmaxf(ad * rstd, EPSV);
    if (lane == 0) gamaOut[row] = g;

    const float c  = rstd * (QB * ASCALE) / g;     // rstd * 126/g
    const float lo = (-QB + EPSV) * ASCALE, hi = (QB - EPSV) * ASCALE;
    auto qz = [&](float vv) -> char {
      return (char)__float2int_rn(fminf(fmaxf((vv - mu) * c, lo), hi));
    };
    char* xqr = xq + (size_t)row * IN_F;
#pragma unroll
    for (int j = 0; j < 8; ++j) {
      i8x4 q = { qz(v[j].x), qz(v[j].y), qz(v[j].z), qz(v[j].w) };
      ((i8x4*)xqr)[lane + 64 * j] = q;
    }
  }
}

// ---------------- GEMM: i8, 128x128 tile, 2-phase double-buffered ----------
// T3 "minimum 2-phase" schedule: stage NEXT K-tile into buf^1, then ds_read +
// MFMA current buf, then ONE __syncthreads (its implicit vmcnt(0) drains the
// next-tile loads, which by then had a full compute phase to land). Removes
// the fully-exposed load latency of the old stage->barrier->compute loop.
// LDS 64 KB (2 x 16KB A + 2 x 16KB B) -> 2 blocks/CU.
// Conflict-free rotated chunk scheme unchanged (measured 0 conflicts).
// Bijective XCD-chunked tile swizzle: 1024 blocks, XCD k owns m-tiles 8k..8k+7
// for all n -> per-XCD working set ~6 MB (A slab 2MB + wb 4MB), L2-friendly.
__global__ __launch_bounds__(256) void gemm_kernel(const char* __restrict__ A,
                                                   const char* __restrict__ B,
                                                   const float* __restrict__ beta,
                                                   const float* __restrict__ gama,
                                                   const float* __restrict__ bias,
                                                   float* __restrict__ out) {
  __shared__ __align__(16) char As[2 * 128 * 128];
  __shared__ __align__(16) char Bs[2 * 128 * 128];

  const int t = threadIdx.x;
  const int wave = t >> 6, lane = t & 63;
  const int bid = blockIdx.x;
  const int swz = (bid & 7) * 128 + (bid >> 3);   // bijective (1024 % 8 == 0)
  const int mBase = (swz >> 4) * 128;             // 64 m-tiles
  const int nBase = (swz & 15) * 128;             // 16 n-tiles
  const int wm = (wave >> 1) * 64;
  const int wn = (wave & 1) * 64;

  i32x4 acc[4][4];
#pragma unroll
  for (int i = 0; i < 4; ++i)
#pragma unroll
    for (int j = 0; j < 4; ++j) {
      i32x4 z = {0, 0, 0, 0};
      acc[i][j] = z;
    }

  // ---- staging geometry: instr j covers rows j*32 + wave*8 + (lane>>3);
  // slot = lane&7 holds global chunk (slot - row)&7  (rotation, 0-conflict)
  const int lr = lane >> 3;
  const int ls = lane & 7;
  const int gch = (ls - lr) & 7;
  const char* aG[4];
  const char* bG[4];
  int lOff[4];
#pragma unroll
  for (int j = 0; j < 4; ++j) {
    const int rowInTile = j * 32 + wave * 8 + lr;
    aG[j] = A + (size_t)(mBase + rowInTile) * IN_F + gch * 16;
    bG[j] = B + (size_t)(nBase + rowInTile) * IN_F + gch * 16;
    lOff[j] = (j * 32 + wave * 8) * 128;   // wave-uniform; HW adds lane*16B
  }

  // ---- fragment geometry: A[m=lane&15][k=(lane>>4)*16+j]; slot=(kh+fr)&7
  const int fr = lane & 15;
  const int kq = lane >> 4;            // 0..3
  int koff[2];
#pragma unroll
  for (int ks = 0; ks < 2; ++ks) koff[ks] = ((ks * 4 + kq + fr) & 7) * 16;

  auto stage = [&](int k0, int buf) {
#pragma unroll
    for (int j = 0; j < 4; ++j) {
      __builtin_amdgcn_global_load_lds(AS1(aG[j] + k0), AS3(As + buf * 16384 + lOff[j]), 16, 0, 0);
      __builtin_amdgcn_global_load_lds(AS1(bG[j] + k0), AS3(Bs + buf * 16384 + lOff[j]), 16, 0, 0);
    }
  };
  auto compute = [&](int buf) {
    const char* aF = As + buf * 16384 + (wm + fr) * 128;
    const char* bF = Bs + buf * 16384 + (wn + fr) * 128;
#pragma unroll
    for (int ks = 0; ks < 2; ++ks) {
      i32x4 af[4], bf[4];
#pragma unroll
      for (int mi = 0; mi < 4; ++mi) af[mi] = *(const i32x4*)(aF + mi * 16 * 128 + koff[ks]);
#pragma unroll
      for (int ni = 0; ni < 4; ++ni) bf[ni] = *(const i32x4*)(bF + ni * 16 * 128 + koff[ks]);
#pragma unroll
      for (int mi = 0; mi < 4; ++mi)
#pragma unroll
        for (int ni = 0; ni < 4; ++ni)
          acc[mi][ni] = __builtin_amdgcn_mfma_i32_16x16x64_i8(af[mi], bf[ni], acc[mi][ni], 0, 0, 0);
    }
  };

  // prologue: tile 0 -> buf 0
  stage(0, 0);
  __syncthreads();                 // implicit vmcnt(0) drain + barrier

  int cur = 0;
  for (int k0 = 128; k0 < IN_F; k0 += 128) {
    stage(k0, cur ^ 1);            // issue next-tile loads (other buffer)
    compute(cur);                  // latency hides under ds_read + MFMA
    __syncthreads();               // drain next-tile loads + barrier
    cur ^= 1;
  }
  compute(cur);                    // last tile, no prefetch

  // ---- epilogue: C/D layout col = lane&15, row = (lane>>4)*4 + reg
  const float qinv = 1.0f / (QB * ASCALE);
  const int orow0 = mBase + wm + (kq << 2);
  const int ocol0 = nBase + wn + fr;
#pragma unroll
  for (int mi = 0; mi < 4; ++mi) {
    const int rbase = orow0 + mi * 16;
    const float g0 = gama[rbase + 0] * qinv;
    const float g1 = gama[rbase + 1] * qinv;
    const float g2 = gama[rbase + 2] * qinv;
    const float g3 = gama[rbase + 3] * qinv;
#pragma unroll
    for (int ni = 0; ni < 4; ++ni) {
      const int c = ocol0 + ni * 16;
      const float bsc = beta[c];
      const float bv  = bias[c];
      float* op = out + (size_t)rbase * OUT_F + c;
      op[0 * OUT_F] = (float)acc[mi][ni][0] * (bsc * g0) + bv;
      op[1 * OUT_F] = (float)acc[mi][ni][1] * (bsc * g1) + bv;
      op[2 * OUT_F] = (float)acc[mi][ni][2] * (bsc * g2) + bv;
      op[3 * OUT_F] = (float)acc[mi][ni][3] * (bsc * g3) + bv;
    }
  }
}

extern "C" void kernel_launch(void* const* d_in, const int* in_sizes, int n_in,
                              void* d_out, int out_size, void* d_ws, size_t ws_size,
                              hipStream_t stream) {
  const float* x      = (const float*)d_in[0];
  const float* weight = (const float*)d_in[1];
  const float* bias   = (const float*)d_in[2];
  float* out = (float*)d_out;

  char* ws = (char*)d_ws;
  char* wbin = ws;                                                  // 4 MB
  char* xq   = ws + (size_t)OUT_F * IN_F;                           // 16 MB
  float* betaW = (float*)(ws + (size_t)OUT_F * IN_F + (size_t)BATCH * IN_F);
  float* gamaX = betaW + OUT_F;

  prep_kernel<<<(OUT_F + BATCH) / 4, 256, 0, stream>>>(x, weight, xq, wbin, gamaX, betaW);
  gemm_kernel<<<OUT_F / 128 * (BATCH / 128), 256, 0, stream>>>(xq, wbin, betaW, gamaX, bias, out);
}

// Round 4
// 164.224 us; speedup vs baseline: 1.0401x; 1.0158x over previous
//
#include <hip/hip_runtime.h>
#include <hip/hip_bf16.h>

#define BATCH 8192
#define IN_F  2048
#define OUT_F 2048
#define QB    7.0f
#define EPSV  1e-5f
#define ASCALE 18.0f            // xq_i8 = round(xq * 18) in [-126,126]

typedef char  i8x4 __attribute__((ext_vector_type(4)));
typedef int   i32x4 __attribute__((ext_vector_type(4)));

#define AS1(p) ((__attribute__((address_space(1))) void*)(p))
#define AS3(p) ((__attribute__((address_space(3))) void*)(p))

// ---------------- Fused preprocessing, one WAVE per row ----------------
// (round-1 verified version, unchanged)
__global__ __launch_bounds__(256) void prep_kernel(const float* __restrict__ x,
                                                   const float* __restrict__ w,
                                                   char* __restrict__ xq,
                                                   char* __restrict__ wb,
                                                   float* __restrict__ gamaOut,
                                                   float* __restrict__ betaOut) {
  const int t = threadIdx.x;
  const int wave = t >> 6, lane = t & 63;
  const int rowId = blockIdx.x * 4 + wave;   // grid = (OUT_F + BATCH) / 4

  if (rowId < OUT_F) {
    const int row = rowId;
    const float4* wr = (const float4*)(w + (size_t)row * IN_F);
    float4 v[8];
#pragma unroll
    for (int j = 0; j < 8; ++j) v[j] = wr[lane + 64 * j];

    float s = 0.0f, sa = 0.0f;
#pragma unroll
    for (int j = 0; j < 8; ++j) {
      s  += v[j].x + v[j].y + v[j].z + v[j].w;
      sa += fabsf(v[j].x) + fabsf(v[j].y) + fabsf(v[j].z) + fabsf(v[j].w);
    }
#pragma unroll
    for (int off = 32; off > 0; off >>= 1) {
      s  += __shfl_xor(s, off, 64);
      sa += __shfl_xor(sa, off, 64);
    }
    const float mu = s * (1.0f / IN_F);
    if (lane == 0) betaOut[row] = sa * (1.0f / IN_F);

    char* wbr = wb + (size_t)row * IN_F;
    auto sgn = [&](float xv) -> char {
      float d = xv - mu;
      return (char)((d > 0.0f) ? 1 : (d < 0.0f ? -1 : 0));
    };
#pragma unroll
    for (int j = 0; j < 8; ++j) {
      i8x4 q = { sgn(v[j].x), sgn(v[j].y), sgn(v[j].z), sgn(v[j].w) };
      ((i8x4*)wbr)[lane + 64 * j] = q;
    }
  } else {
    const int row = rowId - OUT_F;
    const float4* xr = (const float4*)(x + (size_t)row * IN_F);
    float4 v[8];
#pragma unroll
    for (int j = 0; j < 8; ++j) v[j] = xr[lane + 64 * j];

    float s = 0.0f, s2 = 0.0f;
#pragma unroll
    for (int j = 0; j < 8; ++j) {
      s  += v[j].x + v[j].y + v[j].z + v[j].w;
      s2 += v[j].x * v[j].x + v[j].y * v[j].y + v[j].z * v[j].z + v[j].w * v[j].w;
    }
#pragma unroll
    for (int off = 32; off > 0; off >>= 1) {
      s  += __shfl_xor(s, off, 64);
      s2 += __shfl_xor(s2, off, 64);
    }
    const float mu   = s * (1.0f / IN_F);
    const float rstd = rsqrtf(fmaxf(s2 * (1.0f / IN_F) - mu * mu, 0.0f) + EPSV);

    float ad = 0.0f;
#pragma unroll
    for (int j = 0; j < 8; ++j) {
      ad = fmaxf(ad, fmaxf(fmaxf(fabsf(v[j].x - mu), fabsf(v[j].y - mu)),
                           fmaxf(fabsf(v[j].z - mu), fabsf(v[j].w - mu))));
    }
#pragma unroll
    for (int off = 32; off > 0; off >>= 1) ad = fmaxf(ad, __shfl_xor(ad, off, 64));
    const float g = fmaxf(ad * rstd, EPSV);
    if (lane == 0) gamaOut[row] = g;

    const float c  = rstd * (QB * ASCALE) / g;     // rstd * 126/g
    const float lo = (-QB + EPSV) * ASCALE, hi = (QB - EPSV) * ASCALE;
    auto qz = [&](float vv) -> char {
      return (char)__float2int_rn(fminf(fmaxf((vv - mu) * c, lo), hi));
    };
    char* xqr = xq + (size_t)row * IN_F;
#pragma unroll
    for (int j = 0; j < 8; ++j) {
      i8x4 q = { qz(v[j].x), qz(v[j].y), qz(v[j].z), qz(v[j].w) };
      ((i8x4*)xqr)[lane + 64 * j] = q;
    }
  }
}

// ---------------- GEMM: i8, 128x128 tile, BK=128 (r1 proven schedule) -------
// Single 32 KB buffer (5 blocks/CU — cross-block TLP hides the stage drain;
// measured faster than the 64 KB explicit double-buffer, r3 post-mortem).
// Conflict-free rotated chunk scheme (measured 0 conflicts).
// Bijective XCD-chunked tile swizzle (measured FETCH 70 -> 41 MB): XCD k owns
// m-tiles 8k..8k+7 across all n -> per-XCD A slab 2 MB + wb stays L2-warm.
__global__ __launch_bounds__(256) void gemm_kernel(const char* __restrict__ A,
                                                   const char* __restrict__ B,
                                                   const float* __restrict__ beta,
                                                   const float* __restrict__ gama,
                                                   const float* __restrict__ bias,
                                                   float* __restrict__ out) {
  __shared__ __align__(16) char As[128 * 128];
  __shared__ __align__(16) char Bs[128 * 128];

  const int t = threadIdx.x;
  const int wave = t >> 6, lane = t & 63;
  const int bid = blockIdx.x;
  const int swz = (bid & 7) * 128 + (bid >> 3);   // bijective (1024 % 8 == 0)
  const int mBase = (swz >> 4) * 128;             // 64 m-tiles
  const int nBase = (swz & 15) * 128;             // 16 n-tiles
  const int wm = (wave >> 1) * 64;
  const int wn = (wave & 1) * 64;

  i32x4 acc[4][4];
#pragma unroll
  for (int i = 0; i < 4; ++i)
#pragma unroll
    for (int j = 0; j < 4; ++j) {
      i32x4 z = {0, 0, 0, 0};
      acc[i][j] = z;
    }

  // ---- staging: instr j covers rows j*32 + wave*8 + (lane>>3); slot = lane&7
  // fetch global chunk (slot - row)&7  (rotation, measured 0 conflicts)
  const int lr = lane >> 3;
  const int ls = lane & 7;
  const int gch = (ls - lr) & 7;
  const char* aG[4];
  const char* bG[4];
  char* aL[4];
  char* bL[4];
#pragma unroll
  for (int j = 0; j < 4; ++j) {
    const int rowInTile = j * 32 + wave * 8 + lr;
    aG[j] = A + (size_t)(mBase + rowInTile) * IN_F + gch * 16;
    bG[j] = B + (size_t)(nBase + rowInTile) * IN_F + gch * 16;
    aL[j] = As + (j * 32 + wave * 8) * 128;   // wave-uniform; HW adds lane*16B
    bL[j] = Bs + (j * 32 + wave * 8) * 128;
  }

  // ---- fragment: A[m=lane&15][k = (lane>>4)*16 + j]; slot = (kh + fr) & 7
  const int fr = lane & 15;
  const int kq = lane >> 4;            // 0..3
  const char* aF = As + (wm + fr) * 128;
  const char* bF = Bs + (wn + fr) * 128;
  int koff[2];
#pragma unroll
  for (int ks = 0; ks < 2; ++ks) koff[ks] = ((ks * 4 + kq + fr) & 7) * 16;

  for (int k0 = 0; k0 < IN_F; k0 += 128) {
#pragma unroll
    for (int j = 0; j < 4; ++j) {
      __builtin_amdgcn_global_load_lds(AS1(aG[j] + k0), AS3(aL[j]), 16, 0, 0);
      __builtin_amdgcn_global_load_lds(AS1(bG[j] + k0), AS3(bL[j]), 16, 0, 0);
    }
    __syncthreads();

#pragma unroll
    for (int ks = 0; ks < 2; ++ks) {
      i32x4 af[4], bf[4];
#pragma unroll
      for (int mi = 0; mi < 4; ++mi) af[mi] = *(const i32x4*)(aF + mi * 16 * 128 + koff[ks]);
#pragma unroll
      for (int ni = 0; ni < 4; ++ni) bf[ni] = *(const i32x4*)(bF + ni * 16 * 128 + koff[ks]);
#pragma unroll
      for (int mi = 0; mi < 4; ++mi)
#pragma unroll
        for (int ni = 0; ni < 4; ++ni)
          acc[mi][ni] = __builtin_amdgcn_mfma_i32_16x16x64_i8(af[mi], bf[ni], acc[mi][ni], 0, 0, 0);
    }
    __syncthreads();
  }

  // ---- epilogue: C/D layout col = lane&15, row = (lane>>4)*4 + reg
  const float qinv = 1.0f / (QB * ASCALE);
  const int orow0 = mBase + wm + (kq << 2);
  const int ocol0 = nBase + wn + fr;
#pragma unroll
  for (int mi = 0; mi < 4; ++mi) {
    const int rbase = orow0 + mi * 16;
    const float g0 = gama[rbase + 0] * qinv;
    const float g1 = gama[rbase + 1] * qinv;
    const float g2 = gama[rbase + 2] * qinv;
    const float g3 = gama[rbase + 3] * qinv;
#pragma unroll
    for (int ni = 0; ni < 4; ++ni) {
      const int c = ocol0 + ni * 16;
      const float bsc = beta[c];
      const float bv  = bias[c];
      float* op = out + (size_t)rbase * OUT_F + c;
      op[0 * OUT_F] = (float)acc[mi][ni][0] * (bsc * g0) + bv;
      op[1 * OUT_F] = (float)acc[mi][ni][1] * (bsc * g1) + bv;
      op[2 * OUT_F] = (float)acc[mi][ni][2] * (bsc * g2) + bv;
      op[3 * OUT_F] = (float)acc[mi][ni][3] * (bsc * g3) + bv;
    }
  }
}

extern "C" void kernel_launch(void* const* d_in, const int* in_sizes, int n_in,
                              void* d_out, int out_size, void* d_ws, size_t ws_size,
                              hipStream_t stream) {
  const float* x      = (const float*)d_in[0];
  const float* weight = (const float*)d_in[1];
  const float* bias   = (const float*)d_in[2];
  float* out = (float*)d_out;

  char* ws = (char*)d_ws;
  char* wbin = ws;                                                  // 4 MB
  char* xq   = ws + (size_t)OUT_F * IN_F;                           // 16 MB
  float* betaW = (float*)(ws + (size_t)OUT_F * IN_F + (size_t)BATCH * IN_F);
  float* gamaX = betaW + OUT_F;

  prep_kernel<<<(OUT_F + BATCH) / 4, 256, 0, stream>>>(x, weight, xq, wbin, gamaX, betaW);
  gemm_kernel<<<OUT_F / 128 * (BATCH / 128), 256, 0, stream>>>(xq, wbin, betaW, gamaX, bias, out);
}

// Round 5
// 160.701 us; speedup vs baseline: 1.0629x; 1.0219x over previous
//
#include <hip/hip_runtime.h>
#include <hip/hip_bf16.h>

#define BATCH 8192
#define IN_F  2048
#define OUT_F 2048
#define QB    7.0f
#define EPSV  1e-5f
#define ASCALE 18.0f            // xq_i8 = round(xq * 18) in [-126,126]

typedef char  i8x4 __attribute__((ext_vector_type(4)));
typedef int   i32x4 __attribute__((ext_vector_type(4)));

#define AS1(p) ((__attribute__((address_space(1))) void*)(p))
#define AS3(p) ((__attribute__((address_space(3))) void*)(p))

// ---------------- Fused preprocessing, one WAVE per row ----------------
// (round-1 verified version, unchanged)
__global__ __launch_bounds__(256) void prep_kernel(const float* __restrict__ x,
                                                   const float* __restrict__ w,
                                                   char* __restrict__ xq,
                                                   char* __restrict__ wb,
                                                   float* __restrict__ gamaOut,
                                                   float* __restrict__ betaOut) {
  const int t = threadIdx.x;
  const int wave = t >> 6, lane = t & 63;
  const int rowId = blockIdx.x * 4 + wave;   // grid = (OUT_F + BATCH) / 4

  if (rowId < OUT_F) {
    const int row = rowId;
    const float4* wr = (const float4*)(w + (size_t)row * IN_F);
    float4 v[8];
#pragma unroll
    for (int j = 0; j < 8; ++j) v[j] = wr[lane + 64 * j];

    float s = 0.0f, sa = 0.0f;
#pragma unroll
    for (int j = 0; j < 8; ++j) {
      s  += v[j].x + v[j].y + v[j].z + v[j].w;
      sa += fabsf(v[j].x) + fabsf(v[j].y) + fabsf(v[j].z) + fabsf(v[j].w);
    }
#pragma unroll
    for (int off = 32; off > 0; off >>= 1) {
      s  += __shfl_xor(s, off, 64);
      sa += __shfl_xor(sa, off, 64);
    }
    const float mu = s * (1.0f / IN_F);
    if (lane == 0) betaOut[row] = sa * (1.0f / IN_F);

    char* wbr = wb + (size_t)row * IN_F;
    auto sgn = [&](float xv) -> char {
      float d = xv - mu;
      return (char)((d > 0.0f) ? 1 : (d < 0.0f ? -1 : 0));
    };
#pragma unroll
    for (int j = 0; j < 8; ++j) {
      i8x4 q = { sgn(v[j].x), sgn(v[j].y), sgn(v[j].z), sgn(v[j].w) };
      ((i8x4*)wbr)[lane + 64 * j] = q;
    }
  } else {
    const int row = rowId - OUT_F;
    const float4* xr = (const float4*)(x + (size_t)row * IN_F);
    float4 v[8];
#pragma unroll
    for (int j = 0; j < 8; ++j) v[j] = xr[lane + 64 * j];

    float s = 0.0f, s2 = 0.0f;
#pragma unroll
    for (int j = 0; j < 8; ++j) {
      s  += v[j].x + v[j].y + v[j].z + v[j].w;
      s2 += v[j].x * v[j].x + v[j].y * v[j].y + v[j].z * v[j].z + v[j].w * v[j].w;
    }
#pragma unroll
    for (int off = 32; off > 0; off >>= 1) {
      s  += __shfl_xor(s, off, 64);
      s2 += __shfl_xor(s2, off, 64);
    }
    const float mu   = s * (1.0f / IN_F);
    const float rstd = rsqrtf(fmaxf(s2 * (1.0f / IN_F) - mu * mu, 0.0f) + EPSV);

    float ad = 0.0f;
#pragma unroll
    for (int j = 0; j < 8; ++j) {
      ad = fmaxf(ad, fmaxf(fmaxf(fabsf(v[j].x - mu), fabsf(v[j].y - mu)),
                           fmaxf(fabsf(v[j].z - mu), fabsf(v[j].w - mu))));
    }
#pragma unroll
    for (int off = 32; off > 0; off >>= 1) ad = fmaxf(ad, __shfl_xor(ad, off, 64));
    const float g = fmaxf(ad * rstd, EPSV);
    if (lane == 0) gamaOut[row] = g;

    const float c  = rstd * (QB * ASCALE) / g;     // rstd * 126/g
    const float lo = (-QB + EPSV) * ASCALE, hi = (QB - EPSV) * ASCALE;
    auto qz = [&](float vv) -> char {
      return (char)__float2int_rn(fminf(fmaxf((vv - mu) * c, lo), hi));
    };
    char* xqr = xq + (size_t)row * IN_F;
#pragma unroll
    for (int j = 0; j < 8; ++j) {
      i8x4 q = { qz(v[j].x), qz(v[j].y), qz(v[j].z), qz(v[j].w) };
      ((i8x4*)xqr)[lane + 64 * j] = q;
    }
  }
}

// ---------------- GEMM: i8, 256x256 tile, BK=128, dbuf prefetch ------------
// 8 waves (512 thr) 2x4; per-wave 128x64 out via 8x4 frags of 16x16x64 i8
// MFMA -> 64 MFMA per wave per K-step vs 8 staging loads (2x the r4 ratio).
// Double-buffer prefetch (r3 skeleton, proven correct): at 256dd the VGPR
// budget (acc=128) caps at 1 block/CU anyway, so 128 KB LDS costs nothing —
// unlike r3's 128dd case where it halved co-residency.
// Rotation LDS scheme unchanged: row 128 B = 8 chunks of 16 B; slot s of row
// r holds global chunk (s-r)&7; fragment read slot (kh+fr)&7 (0 conflicts).
// Bijective XCD chunking over 256 blocks: XCD k owns swz in [32k,32k+32) ->
// 4 m-panels x all 8 n -> per-XCD A slab 2 MB + wb 4 MB L2-resident.
__global__ __launch_bounds__(512) void gemm_kernel(const char* __restrict__ A,
                                                   const char* __restrict__ B,
                                                   const float* __restrict__ beta,
                                                   const float* __restrict__ gama,
                                                   const float* __restrict__ bias,
                                                   float* __restrict__ out) {
  __shared__ __align__(16) char As[2 * 256 * 128];
  __shared__ __align__(16) char Bs[2 * 256 * 128];

  const int t = threadIdx.x;
  const int wave = t >> 6, lane = t & 63;
  const int bid = blockIdx.x;
  const int swz = (bid & 7) * 32 + (bid >> 3);    // bijective (256 % 8 == 0)
  const int mBase = (swz >> 3) * 256;             // 32 m-tiles
  const int nBase = (swz & 7) * 256;              // 8 n-tiles
  const int wm = (wave >> 2) * 128;               // 2 wave-rows
  const int wn = (wave & 3) * 64;                 // 4 wave-cols

  i32x4 acc[8][4];
#pragma unroll
  for (int i = 0; i < 8; ++i)
#pragma unroll
    for (int j = 0; j < 4; ++j) {
      i32x4 z = {0, 0, 0, 0};
      acc[i][j] = z;
    }

  // ---- staging: instr j covers rows j*64 + wave*8 + (lane>>3); slot = lane&7
  // holds global chunk (slot - row)&7; row&7 == lane>>3 (bases are mult of 8)
  const int lr = lane >> 3;
  const int ls = lane & 7;
  const int gch = (ls - lr) & 7;
  const char* aG[4];
  const char* bG[4];
  int lOff[4];
#pragma unroll
  for (int j = 0; j < 4; ++j) {
    const int rowInTile = j * 64 + wave * 8 + lr;
    aG[j] = A + (size_t)(mBase + rowInTile) * IN_F + gch * 16;
    bG[j] = B + (size_t)(nBase + rowInTile) * IN_F + gch * 16;
    lOff[j] = (j * 64 + wave * 8) * 128;   // wave-uniform; HW adds lane*16B
  }

  // ---- fragment: A[m=lane&15][k=(lane>>4)*16+j]; LDS slot = (kh + fr) & 7
  const int fr = lane & 15;
  const int kq = lane >> 4;            // 0..3
  int koff[2];
#pragma unroll
  for (int ks = 0; ks < 2; ++ks) koff[ks] = ((ks * 4 + kq + fr) & 7) * 16;

  auto stage = [&](int k0, int buf) {
#pragma unroll
    for (int j = 0; j < 4; ++j) {
      __builtin_amdgcn_global_load_lds(AS1(aG[j] + k0), AS3(As + buf * 32768 + lOff[j]), 16, 0, 0);
      __builtin_amdgcn_global_load_lds(AS1(bG[j] + k0), AS3(Bs + buf * 32768 + lOff[j]), 16, 0, 0);
    }
  };
  auto compute = [&](int buf) {
    const char* aF = As + buf * 32768 + (wm + fr) * 128;
    const char* bF = Bs + buf * 32768 + (wn + fr) * 128;
#pragma unroll
    for (int ks = 0; ks < 2; ++ks) {
      i32x4 af[8], bf[4];
#pragma unroll
      for (int mi = 0; mi < 8; ++mi) af[mi] = *(const i32x4*)(aF + mi * 16 * 128 + koff[ks]);
#pragma unroll
      for (int ni = 0; ni < 4; ++ni) bf[ni] = *(const i32x4*)(bF + ni * 16 * 128 + koff[ks]);
#pragma unroll
      for (int mi = 0; mi < 8; ++mi)
#pragma unroll
        for (int ni = 0; ni < 4; ++ni)
          acc[mi][ni] = __builtin_amdgcn_mfma_i32_16x16x64_i8(af[mi], bf[ni], acc[mi][ni], 0, 0, 0);
    }
  };

  // prologue: tile 0 -> buf 0
  stage(0, 0);
  __syncthreads();                 // implicit vmcnt(0) drain + barrier

  int cur = 0;
  for (int k0 = 128; k0 < IN_F; k0 += 128) {
    stage(k0, cur ^ 1);            // issue next-tile loads (other buffer)
    compute(cur);                  // load latency hides under 64 MFMA/wave
    __syncthreads();               // drain next-tile loads + barrier
    cur ^= 1;
  }
  compute(cur);                    // last tile, no prefetch

  // ---- epilogue: C/D layout col = lane&15, row = (lane>>4)*4 + reg
  const float qinv = 1.0f / (QB * ASCALE);
  const int orow0 = mBase + wm + (kq << 2);
  const int ocol0 = nBase + wn + fr;
#pragma unroll
  for (int mi = 0; mi < 8; ++mi) {
    const int rbase = orow0 + mi * 16;
    const float g0 = gama[rbase + 0] * qinv;
    const float g1 = gama[rbase + 1] * qinv;
    const float g2 = gama[rbase + 2] * qinv;
    const float g3 = gama[rbase + 3] * qinv;
#pragma unroll
    for (int ni = 0; ni < 4; ++ni) {
      const int c = ocol0 + ni * 16;
      const float bsc = beta[c];
      const float bv  = bias[c];
      float* op = out + (size_t)rbase * OUT_F + c;
      op[0 * OUT_F] = (float)acc[mi][ni][0] * (bsc * g0) + bv;
      op[1 * OUT_F] = (float)acc[mi][ni][1] * (bsc * g1) + bv;
      op[2 * OUT_F] = (float)acc[mi][ni][2] * (bsc * g2) + bv;
      op[3 * OUT_F] = (float)acc[mi][ni][3] * (bsc * g3) + bv;
    }
  }
}

extern "C" void kernel_launch(void* const* d_in, const int* in_sizes, int n_in,
                              void* d_out, int out_size, void* d_ws, size_t ws_size,
                              hipStream_t stream) {
  const float* x      = (const float*)d_in[0];
  const float* weight = (const float*)d_in[1];
  const float* bias   = (const float*)d_in[2];
  float* out = (float*)d_out;

  char* ws = (char*)d_ws;
  char* wbin = ws;                                                  // 4 MB
  char* xq   = ws + (size_t)OUT_F * IN_F;                           // 16 MB
  float* betaW = (float*)(ws + (size_t)OUT_F * IN_F + (size_t)BATCH * IN_F);
  float* gamaX = betaW + OUT_F;

  prep_kernel<<<(OUT_F + BATCH) / 4, 256, 0, stream>>>(x, weight, xq, wbin, gamaX, betaW);
  gemm_kernel<<<(OUT_F / 256) * (BATCH / 256), 512, 0, stream>>>(xq, wbin, betaW, gamaX, bias, out);
}

// Round 6
// 159.864 us; speedup vs baseline: 1.0685x; 1.0052x over previous
//
#include <hip/hip_runtime.h>
#include <hip/hip_bf16.h>

#define BATCH 8192
#define IN_F  2048
#define OUT_F 2048
#define QB    7.0f
#define EPSV  1e-5f
#define ASCALE 18.0f            // xq_i8 = round(xq * 18) in [-126,126]

typedef char  i8x4 __attribute__((ext_vector_type(4)));
typedef int   i32x4 __attribute__((ext_vector_type(4)));

#define AS1(p) ((__attribute__((address_space(1))) void*)(p))
#define AS3(p) ((__attribute__((address_space(3))) void*)(p))

#define SBAR()  __builtin_amdgcn_s_barrier()
#define LGKM0() do { asm volatile("s_waitcnt lgkmcnt(0)" ::: "memory"); \
                     __builtin_amdgcn_sched_barrier(0); } while (0)
#define WAIT_VM(N) asm volatile("s_waitcnt vmcnt(" #N ")" ::: "memory")

// ---------------- Fused preprocessing, one WAVE per row ----------------
// (round-1 verified version, unchanged)
__global__ __launch_bounds__(256) void prep_kernel(const float* __restrict__ x,
                                                   const float* __restrict__ w,
                                                   char* __restrict__ xq,
                                                   char* __restrict__ wb,
                                                   float* __restrict__ gamaOut,
                                                   float* __restrict__ betaOut) {
  const int t = threadIdx.x;
  const int wave = t >> 6, lane = t & 63;
  const int rowId = blockIdx.x * 4 + wave;   // grid = (OUT_F + BATCH) / 4

  if (rowId < OUT_F) {
    const int row = rowId;
    const float4* wr = (const float4*)(w + (size_t)row * IN_F);
    float4 v[8];
#pragma unroll
    for (int j = 0; j < 8; ++j) v[j] = wr[lane + 64 * j];

    float s = 0.0f, sa = 0.0f;
#pragma unroll
    for (int j = 0; j < 8; ++j) {
      s  += v[j].x + v[j].y + v[j].z + v[j].w;
      sa += fabsf(v[j].x) + fabsf(v[j].y) + fabsf(v[j].z) + fabsf(v[j].w);
    }
#pragma unroll
    for (int off = 32; off > 0; off >>= 1) {
      s  += __shfl_xor(s, off, 64);
      sa += __shfl_xor(sa, off, 64);
    }
    const float mu = s * (1.0f / IN_F);
    if (lane == 0) betaOut[row] = sa * (1.0f / IN_F);

    char* wbr = wb + (size_t)row * IN_F;
    auto sgn = [&](float xv) -> char {
      float d = xv - mu;
      return (char)((d > 0.0f) ? 1 : (d < 0.0f ? -1 : 0));
    };
#pragma unroll
    for (int j = 0; j < 8; ++j) {
      i8x4 q = { sgn(v[j].x), sgn(v[j].y), sgn(v[j].z), sgn(v[j].w) };
      ((i8x4*)wbr)[lane + 64 * j] = q;
    }
  } else {
    const int row = rowId - OUT_F;
    const float4* xr = (const float4*)(x + (size_t)row * IN_F);
    float4 v[8];
#pragma unroll
    for (int j = 0; j < 8; ++j) v[j] = xr[lane + 64 * j];

    float s = 0.0f, s2 = 0.0f;
#pragma unroll
    for (int j = 0; j < 8; ++j) {
      s  += v[j].x + v[j].y + v[j].z + v[j].w;
      s2 += v[j].x * v[j].x + v[j].y * v[j].y + v[j].z * v[j].z + v[j].w * v[j].w;
    }
#pragma unroll
    for (int off = 32; off > 0; off >>= 1) {
      s  += __shfl_xor(s, off, 64);
      s2 += __shfl_xor(s2, off, 64);
    }
    const float mu   = s * (1.0f / IN_F);
    const float rstd = rsqrtf(fmaxf(s2 * (1.0f / IN_F) - mu * mu, 0.0f) + EPSV);

    float ad = 0.0f;
#pragma unroll
    for (int j = 0; j < 8; ++j) {
      ad = fmaxf(ad, fmaxf(fmaxf(fabsf(v[j].x - mu), fabsf(v[j].y - mu)),
                           fmaxf(fabsf(v[j].z - mu), fabsf(v[j].w - mu))));
    }
#pragma unroll
    for (int off = 32; off > 0; off >>= 1) ad = fmaxf(ad, __shfl_xor(ad, off, 64));
    const float g = fmaxf(ad * rstd, EPSV);
    if (lane == 0) gamaOut[row] = g;

    const float c  = rstd * (QB * ASCALE) / g;     // rstd * 126/g
    const float lo = (-QB + EPSV) * ASCALE, hi = (QB - EPSV) * ASCALE;
    auto qz = [&](float vv) -> char {
      return (char)__float2int_rn(fminf(fmaxf((vv - mu) * c, lo), hi));
    };
    char* xqr = xq + (size_t)row * IN_F;
#pragma unroll
    for (int j = 0; j < 8; ++j) {
      i8x4 q = { qz(v[j].x), qz(v[j].y), qz(v[j].z), qz(v[j].w) };
      ((i8x4*)xqr)[lane + 64 * j] = q;
    }
  }
}

// ---------------- GEMM: i8, 256x256, BK=128, 4-phase counted-vmcnt ---------
// T3+T4+T5 port of the 8-phase template. LDS [buf][khalf][256 rows][64 B];
// per K-step 4 phases, each: {ds_read quadrant frags || 2 prefetch gll ->
// s_barrier -> lgkmcnt(0) -> setprio(1) + 16 MFMA + setprio(0) -> s_barrier}.
// K-half staging: tile t+1's h0 issued phases 0-1, h1 phases 2-3; waits are
// vmcnt(4) at end of phases 1 and 3 (NEVER 0 in main loop) -> loads span
// phases, stage drain amortized (m218 mechanism).
// Bank-free rotation for 64-B rows: read slot = (kq + (fr>>1))&3, staged
// chunk kh = 4h + ((ls2 - (lr2>>1))&3); enumerated: every 16-lane group
// hits all 8 bank-quads exactly 2x (2-way = free, m136).
__global__ __launch_bounds__(512, 1) void gemm_kernel(const char* __restrict__ A,
                                                      const char* __restrict__ B,
                                                      const float* __restrict__ beta,
                                                      const float* __restrict__ gama,
                                                      const float* __restrict__ bias,
                                                      float* __restrict__ out) {
  __shared__ __align__(16) char As[2 * 2 * 256 * 64];   // 64 KB
  __shared__ __align__(16) char Bs[2 * 2 * 256 * 64];   // 64 KB

  const int t = threadIdx.x;
  const int wave = t >> 6, lane = t & 63;
  const int bid = blockIdx.x;
  const int swz = (bid & 7) * 32 + (bid >> 3);    // bijective (256 % 8 == 0)
  const int mBase = (swz >> 3) * 256;             // 32 m-tiles
  const int nBase = (swz & 7) * 256;              // 8 n-tiles
  const int wm = (wave >> 2) * 128;               // 2 wave-rows
  const int wn = (wave & 3) * 64;                 // 4 wave-cols

  i32x4 acc[8][4];
#pragma unroll
  for (int i = 0; i < 8; ++i)
#pragma unroll
    for (int j = 0; j < 4; ++j) {
      i32x4 z = {0, 0, 0, 0};
      acc[i][j] = z;
    }

  // ---- staging geometry: instr (h,j) covers rows j*128 + wave*16 + (lane>>2),
  // LDS linear (slot = lane&3); global chunk kh = 4h + ((ls2 - (lr2>>1)) & 3)
  const int lr2 = lane >> 2;
  const int ls2 = lane & 3;
  const int krot = (ls2 - (lr2 >> 1)) & 3;
  const char* aGg = A + (size_t)(mBase + wave * 16 + lr2) * IN_F + krot * 16;
  const char* bGg = B + (size_t)(nBase + wave * 16 + lr2) * IN_F + krot * 16;

  auto stageA = [&](int k0, int buf, int h, int j) {
    __builtin_amdgcn_global_load_lds(
        AS1(aGg + (size_t)j * 128 * IN_F + k0 + h * 64),
        AS3(As + buf * 32768 + h * 16384 + (j * 128 + wave * 16) * 64), 16, 0, 0);
  };
  auto stageB = [&](int k0, int buf, int h, int j) {
    __builtin_amdgcn_global_load_lds(
        AS1(bGg + (size_t)j * 128 * IN_F + k0 + h * 64),
        AS3(Bs + buf * 32768 + h * 16384 + (j * 128 + wave * 16) * 64), 16, 0, 0);
  };

  // ---- fragment geometry: lane = fr + 16*kq; slot = (kq + (fr>>1)) & 3
  const int fr = lane & 15;
  const int kq = lane >> 4;
  const int slot = (kq + (fr >> 1)) & 3;
  const int aRd = (wm + fr) * 64 + slot * 16;
  const int bRd = (wn + fr) * 64 + slot * 16;

  auto ldA = [&](i32x4* af, int buf, int ks, int miBase) {
#pragma unroll
    for (int mi = 0; mi < 4; ++mi)
      af[mi] = *(const i32x4*)(As + buf * 32768 + ks * 16384 + aRd + (miBase + mi) * 1024);
  };
  auto ldB = [&](i32x4* bf, int buf, int ks) {
#pragma unroll
    for (int ni = 0; ni < 4; ++ni)
      bf[ni] = *(const i32x4*)(Bs + buf * 32768 + ks * 16384 + bRd + ni * 1024);
  };
  auto mfma16 = [&](const i32x4* af, const i32x4* bf, int miBase) {
    __builtin_amdgcn_s_setprio(1);
#pragma unroll
    for (int mi = 0; mi < 4; ++mi)
#pragma unroll
      for (int ni = 0; ni < 4; ++ni)
        acc[miBase + mi][ni] =
            __builtin_amdgcn_mfma_i32_16x16x64_i8(af[mi], bf[ni], acc[miBase + mi][ni], 0, 0, 0);
    __builtin_amdgcn_s_setprio(0);
  };

  // ---- prologue: stage tile 0 fully (order: Ah0,Bh0,Ah1,Bh1) ----
  stageA(0, 0, 0, 0); stageA(0, 0, 0, 1);
  stageB(0, 0, 0, 0); stageB(0, 0, 0, 1);
  stageA(0, 0, 1, 0); stageA(0, 0, 1, 1);
  stageB(0, 0, 1, 0); stageB(0, 0, 1, 1);
  WAIT_VM(4);                    // h0 landed (h1 guaranteed at phase-1 wait)
  SBAR();

  int buf = 0;
  for (int k0 = 0; k0 < IN_F; k0 += 128) {
    const bool pf = (k0 + 128 < IN_F);
    const int nk = k0 + 128;
    const int nb = buf ^ 1;
    i32x4 af[4], bf[4];

    // phase 0: ks=0, mi 0-3
    ldB(bf, buf, 0);
    ldA(af, buf, 0, 0);
    if (pf) { stageA(nk, nb, 0, 0); stageA(nk, nb, 0, 1); }
    SBAR(); LGKM0();
    mfma16(af, bf, 0);
    SBAR();

    // phase 1: ks=0, mi 4-7
    ldA(af, buf, 0, 4);
    if (pf) { stageB(nk, nb, 0, 0); stageB(nk, nb, 0, 1); }
    if (pf) { WAIT_VM(4); } else { WAIT_VM(0); }   // this tile's h1 ready
    SBAR(); LGKM0();
    mfma16(af, bf, 4);
    SBAR();

    // phase 2: ks=1, mi 0-3
    ldB(bf, buf, 1);
    ldA(af, buf, 1, 0);
    if (pf) { stageA(nk, nb, 1, 0); stageA(nk, nb, 1, 1); }
    SBAR(); LGKM0();
    mfma16(af, bf, 0);
    SBAR();

    // phase 3: ks=1, mi 4-7
    ldA(af, buf, 1, 4);
    if (pf) { stageB(nk, nb, 1, 0); stageB(nk, nb, 1, 1); }
    if (pf) { WAIT_VM(4); }                         // next tile's h0 ready
    SBAR(); LGKM0();
    mfma16(af, bf, 4);
    SBAR();

    buf = nb;
  }

  // ---- epilogue: C/D layout col = lane&15, row = (lane>>4)*4 + reg
  const float qinv = 1.0f / (QB * ASCALE);
  const int orow0 = mBase + wm + (kq << 2);
  const int ocol0 = nBase + wn + fr;
#pragma unroll
  for (int mi = 0; mi < 8; ++mi) {
    const int rbase = orow0 + mi * 16;
    const float g0 = gama[rbase + 0] * qinv;
    const float g1 = gama[rbase + 1] * qinv;
    const float g2 = gama[rbase + 2] * qinv;
    const float g3 = gama[rbase + 3] * qinv;
#pragma unroll
    for (int ni = 0; ni < 4; ++ni) {
      const int c = ocol0 + ni * 16;
      const float bsc = beta[c];
      const float bv  = bias[c];
      float* op = out + (size_t)rbase * OUT_F + c;
      op[0 * OUT_F] = (float)acc[mi][ni][0] * (bsc * g0) + bv;
      op[1 * OUT_F] = (float)acc[mi][ni][1] * (bsc * g1) + bv;
      op[2 * OUT_F] = (float)acc[mi][ni][2] * (bsc * g2) + bv;
      op[3 * OUT_F] = (float)acc[mi][ni][3] * (bsc * g3) + bv;
    }
  }
}

extern "C" void kernel_launch(void* const* d_in, const int* in_sizes, int n_in,
                              void* d_out, int out_size, void* d_ws, size_t ws_size,
                              hipStream_t stream) {
  const float* x      = (const float*)d_in[0];
  const float* weight = (const float*)d_in[1];
  const float* bias   = (const float*)d_in[2];
  float* out = (float*)d_out;

  char* ws = (char*)d_ws;
  char* wbin = ws;                                                  // 4 MB
  char* xq   = ws + (size_t)OUT_F * IN_F;                           // 16 MB
  float* betaW = (float*)(ws + (size_t)OUT_F * IN_F + (size_t)BATCH * IN_F);
  float* gamaX = betaW + OUT_F;

  prep_kernel<<<(OUT_F + BATCH) / 4, 256, 0, stream>>>(x, weight, xq, wbin, gamaX, betaW);
  gemm_kernel<<<(OUT_F / 256) * (BATCH / 256), 512, 0, stream>>>(xq, wbin, betaW, gamaX, bias, out);
}